// Round 1
// baseline (199.173 us; speedup 1.0000x reference)
//
#include <hip/hip_runtime.h>

#define D 256
#define VOCAB 4096
#define NTOT 16384      // 16 * 32 * 32
#define N_OUT0 4194304  // 16*256*32*32

typedef _Float16 half8 __attribute__((ext_vector_type(8)));
typedef float f32x4 __attribute__((ext_vector_type(4)));

__device__ __forceinline__ void gld16(const void* g, void* l) {
    __builtin_amdgcn_global_load_lds(
        (const __attribute__((address_space(1))) void*)g,
        (__attribute__((address_space(3))) void*)l, 16, 0, 0);
}

__device__ __forceinline__ unsigned long long pack_key(float d, int v) {
    unsigned u = __float_as_uint(d);
    u ^= ((unsigned)((int)u >> 31)) | 0x80000000u;  // monotonic float->uint
    return ((unsigned long long)u << 32) | (unsigned)v;
}

// ---------------- prep: esq, gbest init, out2 zero ----------------
__global__ __launch_bounds__(64) void k_prep(const float* __restrict__ emb,
                                             float* __restrict__ esq,
                                             unsigned long long* __restrict__ gbest,
                                             float* __restrict__ out2) {
    const int v = blockIdx.x, lane = threadIdx.x;
    float4 e = *(const float4*)(emb + (size_t)v * D + lane * 4);
    float s = e.x * e.x + e.y * e.y + e.z * e.z + e.w * e.w;
#pragma unroll
    for (int m = 32; m >= 1; m >>= 1) s += __shfl_xor(s, m, 64);
    if (lane == 0) esq[v] = s;
    if (v < NTOT / 64) gbest[(size_t)v * 64 + lane] = ~0ULL;
    if (v == 0 && lane == 0) out2[0] = 0.0f;
}

// ---------------- fused pack: A (blocks 0..511) and B (512..767) ----------------
// Apk layout (halfs): [bm 64][w 8][hl 2][q 4][r 256][j 8]  tile-window = 16384 halfs
// Bpk layout (halfs): [bn 32][w 8][hl 2][q 4][r 128][j 8]  tile-window = 8192 halfs
__global__ __launch_bounds__(256) void k_pack(const float* __restrict__ h,
                                              const float* __restrict__ emb,
                                              _Float16* __restrict__ Apk,
                                              _Float16* __restrict__ Bpk) {
    __shared__ float S[8192];
    const int tid = threadIdx.x;
    const int bid = blockIdx.x;
    if (bid < 512) {
        const int bm = bid >> 3, w = bid & 7;
        const int b = bm >> 2, p0 = (bm & 3) * 256;
        const float* src = h + ((size_t)b << 18) + p0;
        // fill: S[cl*256 + r] = h[b][w*32+cl][p0+r], coalesced 1KB rows
#pragma unroll 4
        for (int cl = 0; cl < 32; ++cl)
            S[cl * 256 + tid] = src[(size_t)(w * 32 + cl) << 10 | (unsigned)tid];
        __syncthreads();
        _Float16* dstT = Apk + (size_t)bm * 131072 + (size_t)w * 16384;
#pragma unroll
        for (int i = 0; i < 4; ++i) {  // q = i, r = tid
            alignas(16) _Float16 hi[8], lo[8];
#pragma unroll
            for (int j = 0; j < 8; ++j) {
                float vv = S[(i * 8 + j) * 256 + tid];
                _Float16 hv = (_Float16)vv;
                hi[j] = hv;
                lo[j] = (_Float16)(vv - (float)hv);
            }
            _Float16* dst = dstT + i * 2048 + tid * 8;
            *(half8*)dst = *(half8*)hi;
            *(half8*)(dst + 8192) = *(half8*)lo;
        }
    } else {
        const int bid2 = bid - 512;
        const int bn = bid2 >> 3, w = bid2 & 7;
        const int v0 = bn * 128;
        // fill: S[cl*129 + r] = emb[v0+r][w*32+cl]
#pragma unroll 4
        for (int i = 0; i < 16; ++i) {
            int flat = i * 256 + tid;
            int r = flat >> 5, cl = flat & 31;
            S[cl * 129 + r] = emb[(size_t)(v0 + r) * D + w * 32 + cl];
        }
        __syncthreads();
        _Float16* dstT = Bpk + (size_t)bn * 65536 + (size_t)w * 8192;
#pragma unroll
        for (int i = 0; i < 2; ++i) {
            int s = i * 256 + tid;
            int q = s >> 7, r = s & 127;
            alignas(16) _Float16 hi[8], lo[8];
#pragma unroll
            for (int j = 0; j < 8; ++j) {
                float vv = S[(q * 8 + j) * 129 + r];
                _Float16 hv = (_Float16)vv;
                hi[j] = hv;
                lo[j] = (_Float16)(vv - (float)hv);
            }
            _Float16* dst = dstT + q * 1024 + r * 8;
            *(half8*)dst = *(half8*)hi;
            *(half8*)(dst + 4096) = *(half8*)lo;
        }
    }
}

// ---------------- distance GEMM (split-fp16, deep-pipelined) + argmin ----------------
// grid 1024, 512 threads (8 waves as 2m x 4n). Tile 256m x 256n, window K=32 (x hi/lo).
// Double-buffered LDS: As 2x32KB, Bs 2x32KB = 128 KiB. 1 block/CU, 2 waves/SIMD.
// Per window: 3 phases (pass1 hiA.loB, pass2 hiA.hiB, pass3 loA.hiB), each
//   {ds_read frags | issue one 2-load staging chunk} -> s_barrier -> setprio(1) 32xMFMA
//   setprio(0) -> counted vmcnt (6/6/4, never 0 in main loop) -> s_barrier.
// Chunk issue order == consume order: A-hi, B-lo, B-hi, A-lo (2 gld16 each).
// MFMA sequence per (m,v) is bitwise identical to the previous 2-barrier kernel.

#define STAGE_A_HI(W, NB) do { const _Float16* s_ = Ag + (W) * 16384; \
    gld16(s_ + tid * 8, As + (NB) + tid * 8); \
    gld16(s_ + 4096 + tid * 8, As + (NB) + 4096 + tid * 8); } while (0)
#define STAGE_A_LO(W, NB) do { const _Float16* s_ = Ag + (W) * 16384 + 8192; \
    gld16(s_ + tid * 8, As + (NB) + 8192 + tid * 8); \
    gld16(s_ + 4096 + tid * 8, As + (NB) + 12288 + tid * 8); } while (0)
// Bs layout per buffer: [sub 2][hl 2][q 4][r 128][j 8]; sub = n>>7 within tile
#define STAGE_B_LO(W, NB) do { \
    gld16(Bg0 + (W) * 8192 + 4096 + tid * 8, Bs + (NB) + 4096 + tid * 8); \
    gld16(Bg1 + (W) * 8192 + 4096 + tid * 8, Bs + (NB) + 12288 + tid * 8); } while (0)
#define STAGE_B_HI(W, NB) do { \
    gld16(Bg0 + (W) * 8192 + tid * 8, Bs + (NB) + tid * 8); \
    gld16(Bg1 + (W) * 8192 + tid * 8, Bs + (NB) + 8192 + tid * 8); } while (0)

#define LOAD_AF(OFF) do { _Pragma("unroll") \
    for (int mt_ = 0; mt_ < 8; ++mt_) af[mt_] = *(const half8*)(aB + (OFF) + mt_ * 128); } while (0)
#define LOAD_BF(OFF) do { _Pragma("unroll") \
    for (int nt_ = 0; nt_ < 4; ++nt_) bf[nt_] = *(const half8*)(bB + (OFF) + nt_ * 128); } while (0)

#define MFMA32() do { \
    __builtin_amdgcn_s_setprio(1); \
    _Pragma("unroll") \
    for (int mt_ = 0; mt_ < 8; ++mt_) { \
      _Pragma("unroll") \
      for (int nt_ = 0; nt_ < 4; ++nt_) \
        acc[mt_][nt_] = __builtin_amdgcn_mfma_f32_16x16x32_f16(af[mt_], bf[nt_], acc[mt_][nt_], 0, 0, 0); \
    } \
    __builtin_amdgcn_s_setprio(0); \
  } while (0)

#define PHASE_END(N) do { \
    __builtin_amdgcn_sched_barrier(0); \
    asm volatile("s_waitcnt vmcnt(" #N ")" ::: "memory"); \
    __builtin_amdgcn_s_barrier(); } while (0)

__global__ __launch_bounds__(512, 2) void k_gemm(const _Float16* __restrict__ Apk,
                                                 const _Float16* __restrict__ Bpk,
                                                 const float* __restrict__ esq,
                                                 unsigned long long* __restrict__ gbest) {
    __shared__ alignas(16) _Float16 As[32768];  // 2 buf x [hl 2][q 4][r 256][j 8]
    __shared__ alignas(16) _Float16 Bs[32768];  // 2 buf x [sub 2][hl 2][q 4][r 128][j 8]

    const int tid = threadIdx.x;
    const int bid = blockIdx.x;
    // XCD-chunked bijective swizzle (1024 % 8 == 0): XCD x owns bm in [x*8, x*8+8)
    const int swz = (bid & 7) * 128 + (bid >> 3);
    const int bm = swz >> 4, bn = swz & 15;
    const int m0 = bm * 256, n0 = bn * 256;

    const _Float16* Ag = Apk + (size_t)bm * 131072;
    const _Float16* Bg0 = Bpk + (size_t)(2 * bn) * 65536;
    const _Float16* Bg1 = Bpk + (size_t)(2 * bn + 1) * 65536;

    // prologue: stage window 0 fully, in consume order
    STAGE_A_HI(0, 0);
    STAGE_B_LO(0, 0);
    STAGE_B_HI(0, 0);
    STAGE_A_LO(0, 0);

    const int wv = tid >> 6, l = tid & 63;
    const int wm = wv & 1, wn = wv >> 1;          // wave tile: 128m x 64n
    const int quad = l >> 4, j16 = l & 15;
    const int arow = wm * 128 + j16;
    const int brow = (wn & 1) * 64 + j16;
    const int bsub = wn >> 1;

    f32x4 acc[8][4];
#pragma unroll
    for (int i = 0; i < 8; ++i)
#pragma unroll
        for (int j = 0; j < 4; ++j) acc[i][j] = (f32x4)0.0f;

    asm volatile("s_waitcnt vmcnt(4)" ::: "memory");  // A-hi(0)+B-lo(0) landed
    __builtin_amdgcn_s_barrier();

#pragma unroll 1
    for (int w = 0; w < 7; ++w) {
        const int cb = (w & 1) << 14, nb = cb ^ 16384;
        const _Float16* aB = As + cb + quad * 2048 + arow * 8;
        const _Float16* bB = Bs + cb + bsub * 8192 + quad * 1024 + brow * 8;
        half8 af[8], bf[4];

        // phase 1: hiA . loB ; prefetch A-hi(w+1), B-lo(w+1)
        LOAD_AF(0);
        LOAD_BF(4096);
        STAGE_A_HI(w + 1, nb);
        STAGE_B_LO(w + 1, nb);
        __builtin_amdgcn_s_barrier();
        MFMA32();
        PHASE_END(6);  // newest 6 = {A-lo(w), A-hi(w+1), B-lo(w+1)} -> B-hi(w) done

        // phase 2: hiA . hiB (af reused) ; prefetch B-hi(w+1)
        LOAD_BF(0);
        STAGE_B_HI(w + 1, nb);
        __builtin_amdgcn_s_barrier();
        MFMA32();
        PHASE_END(6);  // newest 6 = {A-hi(w+1), B-lo(w+1), B-hi(w+1)} -> A-lo(w) done

        // phase 3: loA . hiB (bf reused) ; prefetch A-lo(w+1)
        LOAD_AF(8192);
        STAGE_A_LO(w + 1, nb);
        __builtin_amdgcn_s_barrier();
        MFMA32();
        PHASE_END(4);  // newest 4 = {B-hi(w+1), A-lo(w+1)} -> A-hi/B-lo(w+1) done
    }
    {   // tail: w = 7, buffer 1, no prefetch; waits drain 2 -> 0
        const _Float16* aB = As + 16384 + quad * 2048 + arow * 8;
        const _Float16* bB = Bs + 16384 + bsub * 8192 + quad * 1024 + brow * 8;
        half8 af[8], bf[4];
        LOAD_AF(0);
        LOAD_BF(4096);
        __builtin_amdgcn_s_barrier();
        MFMA32();
        PHASE_END(2);  // B-hi(7) done
        LOAD_BF(0);
        __builtin_amdgcn_s_barrier();
        MFMA32();
        PHASE_END(0);  // A-lo(7) done
        LOAD_AF(8192);
        __builtin_amdgcn_s_barrier();
        MFMA32();
    }

    // epilogue: dist = esq[v] - 2*dot; argmin with first-index tie-break.
    // red[] reuses dead As buf0 head (keeps total LDS at exactly 128 KiB).
    unsigned long long* red = (unsigned long long*)As;
    __syncthreads();
    if (tid < 256) red[tid] = ~0ULL;
    __syncthreads();

    float es[4];
#pragma unroll
    for (int nt = 0; nt < 4; ++nt) es[nt] = esq[n0 + wn * 64 + nt * 16 + j16];
#pragma unroll
    for (int mt = 0; mt < 8; ++mt) {
#pragma unroll
        for (int r = 0; r < 4; ++r) {
            unsigned long long best = ~0ULL;
#pragma unroll
            for (int nt = 0; nt < 4; ++nt) {
                float dv = es[nt] - 2.0f * acc[mt][nt][r];
                unsigned long long key = pack_key(dv, n0 + wn * 64 + nt * 16 + j16);
                best = key < best ? key : best;
            }
#pragma unroll
            for (int m = 8; m >= 1; m >>= 1) {
                unsigned long long o = __shfl_xor(best, m, 64);
                best = o < best ? o : best;
            }
            if (j16 == 0) atomicMin(&red[wm * 128 + mt * 16 + quad * 4 + r], best);
        }
    }
    __syncthreads();
    if (tid < 256) atomicMin(&gbest[m0 + tid], red[tid]);
}

// ---------------- gather z_q, outputs, loss (atomic) ----------------
__global__ __launch_bounds__(256) void k_gather(const float* __restrict__ h,
                                                const float* __restrict__ emb,
                                                const unsigned long long* __restrict__ gbest,
                                                float* __restrict__ out0,
                                                float* __restrict__ out1,
                                                float* __restrict__ out2) {
    __shared__ float zq[32][260];
    __shared__ float wred[4];
    const int tid = threadIdx.x;
    const int lane = tid & 63;
    const int w = tid >> 6;
    const int n0 = blockIdx.x * 32;
    const int b = n0 >> 10;
    const int p0 = n0 & 1023;
#pragma unroll
    for (int rr = 0; rr < 8; ++rr) {
        int r = w * 8 + rr;
        unsigned idx = (unsigned)(gbest[n0 + r] & 0xFFFFFFFFULL);
        float4 e4 = *(const float4*)(emb + (size_t)idx * D + lane * 4);
        *(float4*)&zq[r][lane * 4] = e4;
    }
    if (tid < 32) {
        unsigned idx = (unsigned)(gbest[n0 + tid] & 0xFFFFFFFFULL);
        out1[n0 + tid] = (float)idx;
    }
    __syncthreads();
    float lsum = 0.0f;
    const size_t base = ((size_t)b * D) << 10;
#pragma unroll 4
    for (int it = 0; it < 32; ++it) {
        int c = it * 8 + (tid >> 5);
        int pp = tid & 31;
        float z = zq[pp][c];
        size_t g = base + ((size_t)c << 10) + p0 + pp;
        float hv = h[g];
        out0[g] = hv + (z - hv);
        float d = hv - z;
        lsum = fmaf(d, d, lsum);
    }
#pragma unroll
    for (int m = 32; m >= 1; m >>= 1) lsum += __shfl_xor(lsum, m, 64);
    if (lane == 0) wred[w] = lsum;
    __syncthreads();
    if (tid == 0)
        atomicAdd(out2, (wred[0] + wred[1] + wred[2] + wred[3]) * (1.0f / (float)N_OUT0));
}

extern "C" void kernel_launch(void* const* d_in, const int* in_sizes, int n_in,
                              void* d_out, int out_size, void* d_ws, size_t ws_size,
                              hipStream_t stream) {
    const float* h = (const float*)d_in[0];
    const float* emb = (const float*)d_in[1];
    float* out0 = (float*)d_out;
    float* out1 = out0 + N_OUT0;
    float* out2 = out1 + NTOT;

    // ws: Apk 16MB | Bpk 4MB | esq 16KB | gbest 128KB   (R2 confirmed ws >= 21.1MB)
    _Float16* Apk = (_Float16*)d_ws;
    _Float16* Bpk = (_Float16*)((char*)d_ws + 16777216);
    float* esq = (float*)((char*)d_ws + 16777216 + 4194304);
    unsigned long long* gbest = (unsigned long long*)((char*)d_ws + 16777216 + 4194304 + 16384);

    hipLaunchKernelGGL(k_prep, dim3(VOCAB), dim3(64), 0, stream, emb, esq, gbest, out2);
    hipLaunchKernelGGL(k_pack, dim3(768), dim3(256), 0, stream, h, emb, Apk, Bpk);
    hipLaunchKernelGGL(k_gemm, dim3(1024), dim3(512), 0, stream, Apk, Bpk, esq, gbest);
    hipLaunchKernelGGL(k_gather, dim3(NTOT / 32), dim3(256), 0, stream, h, emb, gbest, out0, out1, out2);
}